// Round 2
// baseline (527.394 us; speedup 1.0000x reference)
//
#include <hip/hip_runtime.h>

// B=128, K=1024 pairwise-distance adjacency + row softmax.
//
// v3: store-efficiency round. Each block owns 64 rows of one batch
// (8 iterations x 4 waves x 2 rows). Coords staged to LDS once per block,
// each lane's 16 j-points hoisted to 48 VGPRs (shared by all rows).
// Two rows per wave per iteration -> two independent shfl-reduce chains
// interleave (latency of one hides under the other) and stores burst
// 32 x b128 per iteration. Plain (write-back) stores, same path as the
// 6.35 TB/s fill.
//
// Softmax uses the constant shift: diagonal d_ii == 0 exactly (direct
// (xi-xj)^2 form), so row max of exp(-p*d) is exactly 1.0 -> no max pass.

#define K_PTS 1024
#define THREADS 256            // 4 waves
#define ROWS_PER_BLOCK 64
#define ITERS 8                // 8 iters x (4 waves x 2 rows) = 64 rows
#define BLOCKS_PER_BATCH (K_PTS / ROWS_PER_BLOCK)   // 16

typedef float vf4 __attribute__((ext_vector_type(4)));

__device__ __forceinline__ vf4 compute_ev(vf4 vx, vf4 vy, vf4 vz,
                                          float xi, float yi, float zi,
                                          float np) {
  vf4 dx = vx - xi;
  vf4 dy = vy - yi;
  vf4 dz = vz - zi;
  vf4 d  = dx * dx + dy * dy + dz * dz;   // fused to v_fma by the compiler
  vf4 ev;
  ev.x = __expf(__expf(np * d.x) - 1.0f);
  ev.y = __expf(__expf(np * d.y) - 1.0f);
  ev.z = __expf(__expf(np * d.z) - 1.0f);
  ev.w = __expf(__expf(np * d.w) - 1.0f);
  return ev;
}

__global__ __launch_bounds__(THREADS, 4) void adj_softmax_kernel(
    const float* __restrict__ coords,   // [B, K, 3]
    const float* __restrict__ prec,     // [1]
    float* __restrict__ out,            // [B, K, K]
    int B) {
  __shared__ float sx[K_PTS];
  __shared__ float sy[K_PTS];
  __shared__ float sz[K_PTS];

  const int tid   = threadIdx.x;
  const int lane  = tid & 63;
  const int wave  = tid >> 6;
  const int b     = blockIdx.x / BLOCKS_PER_BATCH;
  const int chunk = blockIdx.x % BLOCKS_PER_BATCH;

  const float np = -prec[0];

  // ---- stage this batch's coords into LDS, deinterleaved (x|y|z) ----
  {
    const float* cb = coords + (size_t)b * (K_PTS * 3);
    const int p0 = tid * 4;                       // 4 points per thread
    const float4* src = (const float4*)(cb + (size_t)p0 * 3);
    float4 a0 = src[0];   // {x0,y0,z0,x1}
    float4 a1 = src[1];   // {y1,z1,x2,y2}
    float4 a2 = src[2];   // {z2,x3,y3,z3}
    sx[p0 + 0] = a0.x; sy[p0 + 0] = a0.y; sz[p0 + 0] = a0.z;
    sx[p0 + 1] = a0.w; sy[p0 + 1] = a1.x; sz[p0 + 1] = a1.y;
    sx[p0 + 2] = a1.z; sy[p0 + 2] = a1.w; sz[p0 + 2] = a2.x;
    sx[p0 + 3] = a2.y; sy[p0 + 3] = a2.z; sz[p0 + 3] = a2.w;
  }
  __syncthreads();

  // ---- hoist this lane's 16 j-points into registers (48 VGPRs) ----
  vf4 vx[4], vy[4], vz[4];
#pragma unroll
  for (int t = 0; t < 4; ++t) {
    const int j0 = 4 * lane + 256 * t;
    vx[t] = *(const vf4*)&sx[j0];
    vy[t] = *(const vf4*)&sy[j0];
    vz[t] = *(const vf4*)&sz[j0];
  }

  float* ob = out + (size_t)b * K_PTS * K_PTS;
  const int base = chunk * ROWS_PER_BLOCK;

  for (int it = 0; it < ITERS; ++it) {
    const int r0 = base + it * 8 + wave * 2;      // this wave's row pair
    const int r1 = r0 + 1;
    // per-wave-uniform broadcast reads (same addr across lanes: free)
    const float x0 = sx[r0], y0 = sy[r0], z0 = sz[r0];
    const float x1 = sx[r1], y1 = sy[r1], z1 = sz[r1];

    vf4 e0[4], e1[4];
    float a0 = 0.0f, a1 = 0.0f;

#pragma unroll
    for (int t = 0; t < 4; ++t) {
      vf4 v0 = compute_ev(vx[t], vy[t], vz[t], x0, y0, z0, np);
      vf4 v1 = compute_ev(vx[t], vy[t], vz[t], x1, y1, z1, np);
      e0[t] = v0;
      e1[t] = v1;
      a0 += (v0.x + v0.y) + (v0.z + v0.w);
      a1 += (v1.x + v1.y) + (v1.z + v1.w);
    }

    // ---- two interleaved wave reductions (independent chains) ----
#pragma unroll
    for (int off = 32; off > 0; off >>= 1) {
      a0 += __shfl_xor(a0, off, 64);
      a1 += __shfl_xor(a1, off, 64);
    }
    const float i0 = 1.0f / a0;
    const float i1 = 1.0f / a1;

    // ---- normalized, coalesced float4 stores (write-back path) ----
    float* orow0 = ob + (size_t)r0 * K_PTS;
    float* orow1 = ob + (size_t)r1 * K_PTS;
#pragma unroll
    for (int t = 0; t < 4; ++t) {
      *(vf4*)&orow0[4 * lane + 256 * t] = e0[t] * i0;
      *(vf4*)&orow1[4 * lane + 256 * t] = e1[t] * i1;
    }
  }
}

extern "C" void kernel_launch(void* const* d_in, const int* in_sizes, int n_in,
                              void* d_out, int out_size, void* d_ws, size_t ws_size,
                              hipStream_t stream) {
  const float* coords = (const float*)d_in[0];   // [B, K, 3] fp32
  const float* prec   = (const float*)d_in[1];   // [1] fp32
  float* out = (float*)d_out;                    // [B, K, K] fp32

  const int B = in_sizes[0] / (K_PTS * 3);       // 128
  const int grid = B * BLOCKS_PER_BATCH;         // 128 * 16 = 2048 blocks

  adj_softmax_kernel<<<grid, THREADS, 0, stream>>>(coords, prec, out, B);
}